// Round 3
// baseline (795.840 us; speedup 1.0000x reference)
//
#include <hip/hip_runtime.h>
#include <math.h>

#define H 4096
#define E 64
#define BK 64
#define BM 32
#define TOPK 8
#define EPS 2e-4f

__global__ void init_cnt_kernel(unsigned int* cnt) {
    if (threadIdx.x == 0) cnt[0] = 0u;
}

// f32 GEMM + fused top-9 (gap-checked). lane = expert; wave handles 8 rows.
// Block 256 = 4 waves -> 32 rows; grid T/32 = 512 -> 2 blocks/CU, 2 waves/SIMD.
__global__ __launch_bounds__(256) void router_gemm_kernel(
    const float* __restrict__ A, const float* __restrict__ Wm,
    const float* __restrict__ bias, float* __restrict__ weights,
    float* __restrict__ indices, float* __restrict__ probs,
    unsigned int* __restrict__ cnt, unsigned int* __restrict__ list, int T)
{
    __shared__ float Alds[BM][BK];   // row-major; compute reads are broadcast
    __shared__ float Wlds[E][BK];    // e-major, XOR-swizzled chunks for bank spread

    const int tid  = threadIdx.x;
    const int lane = tid & 63;       // = expert
    const int wid  = tid >> 6;       // wave id, rows [8*wid, 8*wid+8)
    const long row0 = (long)blockIdx.x * BM;

    // staging maps
    const int s_row = tid >> 3;      // 0..31 (A rows)
    const int s_seg = tid & 7;       // 0..7  (A 16B segments)
    const int w_er  = tid >> 4;      // 0..15 (W expert base)
    const int w_c   = tid & 15;      // 0..15 (W 16B chunk)

    float4 acc4[8];
#pragma unroll
    for (int i = 0; i < 8; ++i) acc4[i] = make_float4(0.f, 0.f, 0.f, 0.f);

    const float* aP = A + (row0 + s_row) * (long)H + s_seg * 4;

    // prefetch tile 0 into registers
    float4 pa0 = *(const float4*)(aP);
    float4 pa1 = *(const float4*)(aP + 32);
    float4 pw[4];
#pragma unroll
    for (int j = 0; j < 4; ++j)
        pw[j] = *(const float4*)(Wm + (long)(w_er + j * 16) * H + w_c * 4);

    for (int k0 = 0; k0 < H; k0 += BK) {
        // regs -> LDS
        *(float4*)&Alds[s_row][s_seg * 4]      = pa0;
        *(float4*)&Alds[s_row][32 + s_seg * 4] = pa1;
#pragma unroll
        for (int j = 0; j < 4; ++j) {
            const int e  = w_er + j * 16;
            const int sw = w_c ^ (e & 15);
            *(float4*)&Wlds[e][sw * 4] = pw[j];
        }
        __syncthreads();

        // prefetch next tile (in flight across the FMA block)
        if (k0 + BK < H) {
            const int kn = k0 + BK;
            pa0 = *(const float4*)(aP + kn);
            pa1 = *(const float4*)(aP + kn + 32);
#pragma unroll
            for (int j = 0; j < 4; ++j)
                pw[j] = *(const float4*)(Wm + (long)(w_er + j * 16) * H + kn + w_c * 4);
        }

#pragma unroll
        for (int g = 0; g < 16; ++g) {
            const float4 wv = *(const float4*)&Wlds[lane][(g ^ (lane & 15)) * 4];
#pragma unroll
            for (int i = 0; i < 8; ++i) {
                const float4 av = *(const float4*)&Alds[wid * 8 + i][g * 4];
                acc4[i].x = fmaf(av.x, wv.x, acc4[i].x);
                acc4[i].y = fmaf(av.y, wv.y, acc4[i].y);
                acc4[i].z = fmaf(av.z, wv.z, acc4[i].z);
                acc4[i].w = fmaf(av.w, wv.w, acc4[i].w);
            }
        }
        __syncthreads();
    }

    // ---- epilogue: per-row top-9 via butterfly argmax, gap test, outputs ----
    const float bv = bias[lane];
#pragma unroll 1
    for (int i = 0; i < 8; ++i) {
        const long row = row0 + wid * 8 + i;
        const float logit = (acc4[i].x + acc4[i].y) + (acc4[i].z + acc4[i].w) + bv;

        probs[row * E + lane] = 1.f / (1.f + __expf(-logit));

        float cur = logit;
        float sv[9]; int si[9];
#pragma unroll
        for (int it = 0; it < 9; ++it) {
            float bp = cur; int bi = lane;
#pragma unroll
            for (int off = 32; off >= 1; off >>= 1) {
                const float op = __shfl_xor(bp, off, 64);
                const int   oi = __shfl_xor(bi, off, 64);
                if (op > bp || (op == bp && oi < bi)) { bp = op; bi = oi; }
            }
            sv[it] = bp; si[it] = bi;
            if (lane == bi) cur = -3e38f;   // exclude winner
        }

        float sum = 0.f, mingap = 3e38f;
#pragma unroll
        for (int it = 0; it < TOPK; ++it) {
            sum += 1.f / (1.f + __expf(-sv[it]));
            mingap = fminf(mingap, sv[it] - sv[it + 1]);
        }
        if (lane < TOPK) {
            const float p = 1.f / (1.f + __expf(-sv[lane]));
            weights[row * TOPK + lane] = p / sum;
            indices[row * TOPK + lane] = (float)si[lane];
        }
        if (lane == 0 && mingap < EPS) {
            const unsigned p = atomicAdd(cnt, 1u);
            if (p < (unsigned)T) list[p] = (unsigned)row;
        }
    }
}

// Exact f64 re-resolution of flagged rows. One block per flagged row (strided).
__global__ __launch_bounds__(256) void fixup_kernel(
    const float* __restrict__ A, const float* __restrict__ Wm,
    const float* __restrict__ bias, float* __restrict__ weights,
    float* __restrict__ indices, const unsigned int* __restrict__ cnt,
    const unsigned int* __restrict__ list, int T)
{
    __shared__ double Llds[E];
    const int tid = threadIdx.x, lane = tid & 63, wid = tid >> 6;
    unsigned int count = cnt[0];
    if (count > (unsigned)T) count = (unsigned)T;

    for (unsigned idx = blockIdx.x; idx < count; idx += gridDim.x) {
        const long row = (long)list[idx];
#pragma unroll 1
        for (int ee = 0; ee < 16; ++ee) {
            const int e = wid * 16 + ee;
            double part = 0.0;
            for (int j = 0; j < 16; ++j) {
                const int k = j * 256 + lane * 4;
                const float4 a = *(const float4*)(A + row * H + k);
                const float4 w = *(const float4*)(Wm + (long)e * H + k);
                part = fma((double)a.x, (double)w.x, part);
                part = fma((double)a.y, (double)w.y, part);
                part = fma((double)a.z, (double)w.z, part);
                part = fma((double)a.w, (double)w.w, part);
            }
#pragma unroll
            for (int off = 32; off >= 1; off >>= 1)
                part += __shfl_xor(part, off, 64);
            if (lane == 0) Llds[e] = part + (double)bias[e];
        }
        __syncthreads();
        if (tid == 0) {
            unsigned long long taken = 0ull;
            float sv[TOPK]; int si[TOPK]; float sum = 0.f;
            for (int it = 0; it < TOPK; ++it) {
                double best = -1.0e300; int bi = 0;
                for (int j = 0; j < E; ++j)
                    if (!((taken >> j) & 1ull) && Llds[j] > best) { best = Llds[j]; bi = j; }
                taken |= 1ull << bi;
                const float p = 1.f / (1.f + __expf(-(float)best));
                sv[it] = p; si[it] = bi; sum += p;
            }
            for (int it = 0; it < TOPK; ++it) {
                weights[row * TOPK + it] = sv[it] / sum;
                indices[row * TOPK + it] = (float)si[it];
            }
        }
        __syncthreads();
    }
}

extern "C" void kernel_launch(void* const* d_in, const int* in_sizes, int n_in,
                              void* d_out, int out_size, void* d_ws, size_t ws_size,
                              hipStream_t stream) {
    const float* A    = (const float*)d_in[0];   // [T, H]
    const float* W    = (const float*)d_in[1];   // [E, H]
    const float* bias = (const float*)d_in[2];   // [E]
    const int T = in_sizes[0] / H;               // 16384

    float* out     = (float*)d_out;
    float* weights = out;                          // [T, 8]
    float* indices = out + (size_t)T * TOPK;       // [T, 8] (float-valued)
    float* probs   = out + (size_t)T * 2 * TOPK;   // [T, 64]

    unsigned int* cnt  = (unsigned int*)d_ws;      // [1]
    unsigned int* list = cnt + 8;                  // [T] flagged row ids

    hipLaunchKernelGGL(init_cnt_kernel, dim3(1), dim3(64), 0, stream, cnt);
    hipLaunchKernelGGL(router_gemm_kernel, dim3(T / BM), dim3(256), 0, stream,
                       A, W, bias, weights, indices, probs, cnt, list, T);
    hipLaunchKernelGGL(fixup_kernel, dim3(256), dim3(256), 0, stream,
                       A, W, bias, weights, indices, cnt, list, T);
}